// Round 2
// baseline (17483.969 us; speedup 1.0000x reference)
//
#include <hip/hip_runtime.h>
#include <stdint.h>

// ---------------------------------------------------------------------------
// Persistent-RNN 2-layer LSTM decoder (B=64,H=1024,OUT=512,SEQ=256), MI355X.
// 256 WGs (1/CU) x 256 thr. Weights fp16 in LDS (loaded once). Activations
// fp16 double-buffered in d_ws; flag-array sync with monotonic step tags.
// Gates/c/h computed fp32 (MFMA f32 accumulate). encoder_output is UNUSED
// by the reference (decoder feeds back its own output).
// ---------------------------------------------------------------------------

#define NBLK 256
#define NTHR 256
#define HDIM 1024
#define ODIM 512
#define BDIM 64
#define SEQL 256

typedef _Float16 v8h __attribute__((ext_vector_type(8)));
typedef float    v4f __attribute__((ext_vector_type(4)));

// LDS layout: per k-step, 64 lanes x 16B contiguous = 1024B (conflict-free b128)
#define WL0_NS 48                       // K = 512+1024
#define WL1_NS 64                       // K = 1024+1024
#define WFC_NS 32                       // K = 1024
#define WL0_OFF 0
#define WL1_OFF (WL0_NS*1024)
#define WFC_OFF (WL1_OFF + WL1_NS*1024)
#define SMEM_BYTES (WFC_OFF + WFC_NS*1024)   // 147456 B

// workspace layout (bytes)
#define YB_SZ  (BDIM*ODIM*2)
#define HB_SZ  (BDIM*HDIM*2)
#define YB_OFF 0
#define H0B_OFF (2*YB_SZ)
#define H1B_OFF (H0B_OFF + 2*HB_SZ)
#define FLG_OFF (H1B_OFF + 2*HB_SZ)
#define FY_OFF  (FLG_OFF)
#define FH0_OFF (FLG_OFF + 1024)
#define FH1_OFF (FLG_OFF + 2048)
#define FLG_BYTES 3072
#define WS_NEED (FLG_OFF + FLG_BYTES)

__device__ __forceinline__ float fsig(float x)   { return 1.0f / (1.0f + __expf(-x)); }
__device__ __forceinline__ float ftanhf(float x) { return 1.0f - 2.0f / (__expf(2.0f*x) + 1.0f); }

__device__ __forceinline__ void wait_flags(const unsigned int* flags, int n, unsigned int tag){
  int tid = threadIdx.x;
  if (tid < n){
    while (__hip_atomic_load(flags + tid, __ATOMIC_RELAXED, __HIP_MEMORY_SCOPE_AGENT) < tag){
      __builtin_amdgcn_s_sleep(8);
    }
  }
  __syncthreads();
  __threadfence();   // acquire: no later load may see stale data (device scope)
}

__device__ __forceinline__ void publish_flag(unsigned int* flag, unsigned int tag){
  __syncthreads();   // all waves' stores issued
  if (threadIdx.x == 0){
    __threadfence(); // release: drain h/y stores to device scope before flag
    __hip_atomic_store(flag, tag, __ATOMIC_RELAXED, __HIP_MEMORY_SCOPE_AGENT);
  }
}

// K-loop over NC chunks of 8 k-steps; A from global (2-chunk prefetch), B from LDS.
// k-slot mapping: lane l supplies k = s*32 + (l>>4)*8 + j for both A and B (any
// consistent bijection is valid — MFMA K-reduction is permutation invariant).
template<int NC>
__device__ __forceinline__ v4f gemm_phase(const char* const cb[], const char* wl, v4f acc){
  v8h A[3][8];
  #pragma unroll
  for (int p = 0; p < 2; p++){
    #pragma unroll
    for (int j = 0; j < 8; j++) A[p][j] = *(const v8h*)(cb[p] + (size_t)j*64);
  }
  #pragma unroll
  for (int c = 0; c < NC; c++){
    const int cur = c % 3, nx = (c + 2) % 3;
    if (c + 2 < NC){
      #pragma unroll
      for (int j = 0; j < 8; j++) A[nx][j] = *(const v8h*)(cb[c+2] + (size_t)j*64);
    }
    #pragma unroll
    for (int j = 0; j < 8; j++){
      v8h B = *(const v8h*)(wl + (size_t)(c*8 + j)*1024);
      acc = __builtin_amdgcn_mfma_f32_16x16x32_f16(A[cur][j], B, acc, 0, 0, 0);
    }
  }
  return acc;
}

// LSTM epilogue: acc[r] = gate pre-act for (batch rb+r, col l15). cols are
// (unit_local*4 + gate); i/f/g/o live on 4 adjacent lanes -> shfl_xor gather.
__device__ __forceinline__ void lstm_epi(v4f acc, float bias, float* cs,
                                         _Float16* hdst, int rb, int unit, int gidx){
  #pragma unroll
  for (int r = 0; r < 4; r++){
    float v  = acc[r] + bias;
    float x1 = __shfl_xor(v, 1);
    float x2 = __shfl_xor(v, 2);
    float x3 = __shfl_xor(v, 3);
    float vi = (gidx==0)?v :(gidx==1)?x1:(gidx==2)?x2:x3;
    float vf = (gidx==1)?v :(gidx==0)?x1:(gidx==3)?x2:x3;
    float vg = (gidx==2)?v :(gidx==3)?x1:(gidx==0)?x2:x3;
    float vo = (gidx==3)?v :(gidx==2)?x1:(gidx==1)?x2:x3;
    float ii = fsig(vi), ff = fsig(vf), gg = ftanhf(vg), oo = fsig(vo);
    float cn = ff*cs[r] + ii*gg;
    cs[r] = cn;
    float hn = oo * ftanhf(cn);
    if (gidx == 0) hdst[(size_t)(rb + r)*HDIM + unit] = (_Float16)hn;
  }
}

__global__ void init_kernel(const float* __restrict__ h0,
                            _Float16* __restrict__ h0b1, _Float16* __restrict__ h1b1,
                            _Float16* __restrict__ yb1){
  int i = blockIdx.x*256 + threadIdx.x;          // grid 256x256 = 65536
  if (i < BDIM*HDIM){
    h0b1[i] = (_Float16)h0[i];
    h1b1[i] = (_Float16)h0[BDIM*HDIM + i];
  }
  if (i < BDIM*ODIM) yb1[i] = (_Float16)(-2.0f); // SOS token
}

__launch_bounds__(NTHR, 1)
__global__ void decoder_kernel(
    const float* __restrict__ Wih0, const float* __restrict__ Whh0,
    const float* __restrict__ bih0, const float* __restrict__ bhh0,
    const float* __restrict__ Wih1, const float* __restrict__ Whh1,
    const float* __restrict__ bih1, const float* __restrict__ bhh1,
    const float* __restrict__ Wfc,  const float* __restrict__ bfc,
    const float* __restrict__ c0in, float* __restrict__ out,
    char* __restrict__ ws)
{
  extern __shared__ char smem[];
  const int bid = blockIdx.x;
  const int tid = threadIdx.x;
  const int wv  = tid >> 6;
  const int ln  = tid & 63;
  const int l15 = ln & 15;
  const int lq  = ln >> 4;
  const int u0  = bid * 4;

  _Float16* yb[2]  = { (_Float16*)(ws + YB_OFF),  (_Float16*)(ws + YB_OFF  + YB_SZ) };
  _Float16* h0b[2] = { (_Float16*)(ws + H0B_OFF), (_Float16*)(ws + H0B_OFF + HB_SZ) };
  _Float16* h1b[2] = { (_Float16*)(ws + H1B_OFF), (_Float16*)(ws + H1B_OFF + HB_SZ) };
  unsigned int* fy  = (unsigned int*)(ws + FY_OFF);
  unsigned int* fh0 = (unsigned int*)(ws + FH0_OFF);
  unsigned int* fh1 = (unsigned int*)(ws + FH1_OFF);

  // ---- one-time: weights fp32->fp16 into LDS, in exact fragment order ----
  for (int slot = tid; slot < WL0_NS*64; slot += NTHR){
    int s = slot >> 6, l = slot & 63;
    int r16 = l & 15, q = l >> 4;
    int grow = (r16 & 3)*HDIM + u0 + (r16 >> 2);
    int kb = s*32 + q*8;
    const float* src; int k0;
    if (kb < ODIM){ src = Wih0 + (size_t)grow*ODIM; k0 = kb; }
    else          { src = Whh0 + (size_t)grow*HDIM; k0 = kb - ODIM; }
    v8h hv;
    #pragma unroll
    for (int j = 0; j < 8; j++) hv[j] = (_Float16)src[k0 + j];
    *(v8h*)(smem + WL0_OFF + s*1024 + l*16) = hv;
  }
  for (int slot = tid; slot < WL1_NS*64; slot += NTHR){
    int s = slot >> 6, l = slot & 63;
    int r16 = l & 15, q = l >> 4;
    int grow = (r16 & 3)*HDIM + u0 + (r16 >> 2);
    int kb = s*32 + q*8;
    const float* src; int k0;
    if (kb < HDIM){ src = Wih1 + (size_t)grow*HDIM; k0 = kb; }
    else          { src = Whh1 + (size_t)grow*HDIM; k0 = kb - HDIM; }
    v8h hv;
    #pragma unroll
    for (int j = 0; j < 8; j++) hv[j] = (_Float16)src[k0 + j];
    *(v8h*)(smem + WL1_OFF + s*1024 + l*16) = hv;
  }
  if (bid < 32){
    for (int slot = tid; slot < WFC_NS*64; slot += NTHR){
      int s = slot >> 6, l = slot & 63;
      int r16 = l & 15, q = l >> 4;
      const float* src = Wfc + (size_t)(bid*16 + r16)*HDIM;
      int k0 = s*32 + q*8;
      v8h hv;
      #pragma unroll
      for (int j = 0; j < 8; j++) hv[j] = (_Float16)src[k0 + j];
      *(v8h*)(smem + WFC_OFF + s*1024 + l*16) = hv;
    }
  }
  __syncthreads();

  // ---- per-lane constants ----
  const int gidx = l15 & 3;
  const int unit = u0 + (l15 >> 2);
  const int growL = gidx*HDIM + unit;
  const float bias0 = bih0[growL] + bhh0[growL];
  const float bias1 = bih1[growL] + bhh1[growL];
  float biasf = 0.f;
  if (bid < 32) biasf = bfc[bid*16 + l15];

  const int rb = wv*16 + lq*4;     // batch row base for D-frag
  float cs0[4], cs1[4];
  #pragma unroll
  for (int r = 0; r < 4; r++){
    int b = rb + r;
    cs0[r] = c0in[(size_t)(0*BDIM + b)*HDIM + unit];
    cs1[r] = c0in[(size_t)(1*BDIM + b)*HDIM + unit];
  }

  const int row = wv*16 + l15;     // A-frag batch row
  const size_t aoffY = (size_t)row*ODIM*2 + (size_t)lq*16;
  const size_t aoffH = (size_t)row*HDIM*2 + (size_t)lq*16;
  const char* wl0 = smem + WL0_OFF + ln*16;
  const char* wl1 = smem + WL1_OFF + ln*16;
  const char* wlf = smem + WFC_OFF + ln*16;

  for (int t = 0; t < SEQL; t++){
    const int pi = (t + 1) & 1;    // prev-step parity
    const int pc = t & 1;          // cur-step parity

    // ---------------- Layer 0: x = [ y[t-1] ; h0[t-1] ] ----------------
    if (t > 0) wait_flags(fy, 32, (unsigned int)t);
    {
      const char* ysrc = (const char*)yb[pi]  + aoffY;
      const char* hsrc = (const char*)h0b[pi] + aoffH;
      const char* cb[6] = { ysrc, ysrc+512, hsrc, hsrc+512, hsrc+1024, hsrc+1536 };
      v4f acc = {0.f, 0.f, 0.f, 0.f};
      acc = gemm_phase<6>(cb, wl0, acc);
      lstm_epi(acc, bias0, cs0, h0b[pc], rb, unit, gidx);
    }
    publish_flag(&fh0[bid], (unsigned int)(t + 1));

    // ---------------- Layer 1: x = [ h0[t] ; h1[t-1] ] -----------------
    wait_flags(fh0, 256, (unsigned int)(t + 1));
    {
      const char* a = (const char*)h0b[pc] + aoffH;
      const char* b = (const char*)h1b[pi] + aoffH;
      const char* cb[8] = { a, a+512, a+1024, a+1536, b, b+512, b+1024, b+1536 };
      v4f acc = {0.f, 0.f, 0.f, 0.f};
      acc = gemm_phase<8>(cb, wl1, acc);
      lstm_epi(acc, bias1, cs1, h1b[pc], rb, unit, gidx);
    }
    publish_flag(&fh1[bid], (unsigned int)(t + 1));

    // ---------------- FC (blocks 0..31): y = relu(h1[t] @ Wfc^T + b) ----
    if (bid < 32){
      wait_flags(fh1, 256, (unsigned int)(t + 1));
      const char* f = (const char*)h1b[pc] + aoffH;
      const char* cb[4] = { f, f+512, f+1024, f+1536 };
      v4f acc = {0.f, 0.f, 0.f, 0.f};
      acc = gemm_phase<4>(cb, wlf, acc);
      _Float16* ydst = yb[pc];
      #pragma unroll
      for (int r = 0; r < 4; r++){
        float v = fmaxf(acc[r] + biasf, 0.f);
        int b = rb + r;
        int o = bid*16 + l15;
        out[((size_t)b*SEQL + t)*ODIM + o] = v;
        ydst[(size_t)b*ODIM + o] = (_Float16)v;
      }
      publish_flag(&fy[bid], (unsigned int)(t + 1));
    }
  }
}

extern "C" void kernel_launch(void* const* d_in, const int* in_sizes, int n_in,
                              void* d_out, int out_size, void* d_ws, size_t ws_size,
                              hipStream_t stream){
  (void)in_sizes; (void)n_in; (void)out_size;
  if (ws_size < (size_t)WS_NEED) return;

  const float* h0   = (const float*)d_in[1];
  const float* c0   = (const float*)d_in[2];
  const float* Wih0 = (const float*)d_in[3];
  const float* Whh0 = (const float*)d_in[4];
  const float* bih0 = (const float*)d_in[5];
  const float* bhh0 = (const float*)d_in[6];
  const float* Wih1 = (const float*)d_in[7];
  const float* Whh1 = (const float*)d_in[8];
  const float* bih1 = (const float*)d_in[9];
  const float* bhh1 = (const float*)d_in[10];
  const float* Wfc  = (const float*)d_in[11];
  const float* bfc  = (const float*)d_in[12];
  float* out = (float*)d_out;
  char* ws = (char*)d_ws;

  (void)hipMemsetAsync(ws + FLG_OFF, 0, FLG_BYTES, stream);
  hipLaunchKernelGGL(init_kernel, dim3(256), dim3(256), 0, stream,
                     h0,
                     (_Float16*)(ws + H0B_OFF + HB_SZ),
                     (_Float16*)(ws + H1B_OFF + HB_SZ),
                     (_Float16*)(ws + YB_OFF + YB_SZ));

  (void)hipFuncSetAttribute((const void*)decoder_kernel,
                            hipFuncAttributeMaxDynamicSharedMemorySize, SMEM_BYTES);
  hipLaunchKernelGGL(decoder_kernel, dim3(NBLK), dim3(NTHR), SMEM_BYTES, stream,
                     Wih0, Whh0, bih0, bhh0, Wih1, Whh1, bih1, bhh1,
                     Wfc, bfc, c0, out, ws);
}

// Round 3
// 8403.918 us; speedup vs baseline: 2.0805x; 2.0805x over previous
//
#include <hip/hip_runtime.h>
#include <stdint.h>

// ---------------------------------------------------------------------------
// Persistent-RNN 2-layer LSTM decoder (B=64,H=1024,OUT=512,SEQ=256), MI355X.
// 256 WGs (1/CU) x 256 thr. Weights fp16 in LDS (loaded once).
// R3: fence-free coherence — all cross-block data moves via agent-scope
// relaxed atomics (sc0 sc1 -> L3 coherent point). No buffer_wbl2/inv.
// Critical-path K-split: recurrent halves computed in wait slots.
// ---------------------------------------------------------------------------

#define NBLK 256
#define NTHR 256
#define HDIM 1024
#define ODIM 512
#define BDIM 64
#define SEQL 256

typedef _Float16 v8h __attribute__((ext_vector_type(8)));
typedef float    v4f __attribute__((ext_vector_type(4)));

// LDS: per k-slice, 64 lanes x 16B contiguous = 1024B (conflict-free b128)
#define WL0_NS 48                       // K = 512(y) + 1024(h0)
#define WL1_NS 64                       // K = 1024(h0) + 1024(h1)
#define WFC_NS 32                       // K = 1024
#define WL0_OFF 0
#define WL1_OFF (WL0_NS*1024)
#define WFC_OFF (WL1_OFF + WL1_NS*1024)
#define SMEM_BYTES (WFC_OFF + WFC_NS*1024)   // 147456 B

// workspace layout (bytes)
#define YB_SZ  (BDIM*ODIM*2)
#define HB_SZ  (BDIM*HDIM*2)
#define YB_OFF 0
#define H0B_OFF (2*YB_SZ)
#define H1B_OFF (H0B_OFF + 2*HB_SZ)
#define FLG_OFF (H1B_OFF + 2*HB_SZ)
#define FY_OFF  (FLG_OFF)                    // 32 flags x 64B
#define FH0_OFF (FLG_OFF + 2048)             // 256 flags x 64B
#define FH1_OFF (FH0_OFF + 16384)
#define FLG_BYTES (2048 + 16384 + 16384)
#define WS_NEED (FLG_OFF + FLG_BYTES)
#define FSTRIDE 16                           // uints per flag (64B padding)

__device__ __forceinline__ float fsig(float x)   { return 1.0f / (1.0f + __expf(-x)); }
__device__ __forceinline__ float ftanhf(float x) { return 1.0f - 2.0f / (__expf(2.0f*x) + 1.0f); }

// coherent 16B load = two 8B agent-scope relaxed atomic loads (sc0 sc1; bypass
// stale local L2, served by IF$/L3). Compiler-tracked (no manual vmcnt).
__device__ __forceinline__ v8h cload16(const char* p){
  union { unsigned long long u[2]; v8h h; } x;
  x.u[0] = __hip_atomic_load((const unsigned long long*)p,     __ATOMIC_RELAXED, __HIP_MEMORY_SCOPE_AGENT);
  x.u[1] = __hip_atomic_load((const unsigned long long*)(p+8), __ATOMIC_RELAXED, __HIP_MEMORY_SCOPE_AGENT);
  return x.h;
}

__device__ __forceinline__ void wait_flags(const unsigned int* flags, int n, unsigned int tag){
  if ((int)threadIdx.x < n){
    while (__hip_atomic_load(flags + threadIdx.x*FSTRIDE, __ATOMIC_RELAXED, __HIP_MEMORY_SCOPE_AGENT) < tag){
      __builtin_amdgcn_s_sleep(1);
    }
  }
  __syncthreads();
}

// Data stores are all sc1 write-through atomics; barrier drains each wave's
// vmcnt; thread0's extra vmcnt(0) orders its flag store after its own.
__device__ __forceinline__ void publish_flag(unsigned int* flag, unsigned int tag){
  __syncthreads();
  if (threadIdx.x == 0){
    asm volatile("s_waitcnt vmcnt(0)" ::: "memory");
    __hip_atomic_store(flag, tag, __ATOMIC_RELAXED, __HIP_MEMORY_SCOPE_AGENT);
  }
}

// K-loop: NC chunks of 256 K-cols (8 MFMAs each); A coherent from ws, B from LDS.
// k-slot bijection matches the LDS fill (lane l, slice j -> k = s*32+(l>>4)*8+j).
template<int NC>
__device__ __forceinline__ v4f gemm_phase(const char* const cb[], const char* wl, v4f acc){
  v8h A[4][8];
  constexpr int PF = (NC < 3) ? NC : 3;
  #pragma unroll
  for (int p = 0; p < PF; p++){
    #pragma unroll
    for (int j = 0; j < 8; j++) A[p][j] = cload16(cb[p] + (size_t)j*64);
  }
  #pragma unroll
  for (int c = 0; c < NC; c++){
    const int cur = c & 3, nx = (c + 3) & 3;
    if (c + 3 < NC){
      #pragma unroll
      for (int j = 0; j < 8; j++) A[nx][j] = cload16(cb[c+3] + (size_t)j*64);
    }
    #pragma unroll
    for (int j = 0; j < 8; j++){
      v8h B = *(const v8h*)(wl + (size_t)(c*8 + j)*1024);
      acc = __builtin_amdgcn_mfma_f32_16x16x32_f16(A[cur][j], B, acc, 0, 0, 0);
    }
  }
  return acc;
}

// Same A-stream feeding two B matrices (L1 input-part + next-step L0 recurrent).
__device__ __forceinline__ void gemm_dual4(const char* const cb[], const char* wlA,
                                           const char* wlB, v4f& accA, v4f& accB){
  v8h A[4][8];
  #pragma unroll
  for (int p = 0; p < 3; p++){
    #pragma unroll
    for (int j = 0; j < 8; j++) A[p][j] = cload16(cb[p] + (size_t)j*64);
  }
  #pragma unroll
  for (int c = 0; c < 4; c++){
    const int cur = c & 3, nx = (c + 3) & 3;
    if (c + 3 < 4){
      #pragma unroll
      for (int j = 0; j < 8; j++) A[nx][j] = cload16(cb[c+3] + (size_t)j*64);
    }
    #pragma unroll
    for (int j = 0; j < 8; j++){
      v8h BA = *(const v8h*)(wlA + (size_t)(c*8 + j)*1024);
      accA = __builtin_amdgcn_mfma_f32_16x16x32_f16(A[cur][j], BA, accA, 0, 0, 0);
      v8h BB = *(const v8h*)(wlB + (size_t)(c*8 + j)*1024);
      accB = __builtin_amdgcn_mfma_f32_16x16x32_f16(A[cur][j], BB, accB, 0, 0, 0);
    }
  }
}

// LSTM epilogue: gate gather via xor1/2/3; h packed 4 units -> one 8B sc1 store.
__device__ __forceinline__ void lstm_epi_pack(v4f acc, float bias, float* cs,
                                              char* hbase, int l15, int gidx){
  #pragma unroll
  for (int r = 0; r < 4; r++){
    float v  = acc[r] + bias;
    float x1 = __shfl_xor(v, 1);
    float x2 = __shfl_xor(v, 2);
    float x3 = __shfl_xor(v, 3);
    float vi = (gidx==0)?v :(gidx==1)?x1:(gidx==2)?x2:x3;
    float vf = (gidx==1)?v :(gidx==0)?x1:(gidx==3)?x2:x3;
    float vg = (gidx==2)?v :(gidx==3)?x1:(gidx==0)?x2:x3;
    float vo = (gidx==3)?v :(gidx==2)?x1:(gidx==1)?x2:x3;
    float ii = fsig(vi), ff = fsig(vf), gg = ftanhf(vg), oo = fsig(vo);
    float cn = ff*cs[r] + ii*gg;
    cs[r] = cn;
    float hn = oo * ftanhf(cn);
    unsigned int uv = (unsigned int)__builtin_bit_cast(unsigned short, (_Float16)hn);
    unsigned int o4 = (unsigned int)__shfl_xor((int)uv, 4);
    unsigned int pr = uv | (o4 << 16);
    unsigned int o8 = (unsigned int)__shfl_xor((int)pr, 8);
    if (l15 == 0){
      unsigned long long full = (unsigned long long)pr | ((unsigned long long)o8 << 32);
      __hip_atomic_store((unsigned long long*)(hbase + (size_t)r*(HDIM*2)), full,
                         __ATOMIC_RELAXED, __HIP_MEMORY_SCOPE_AGENT);
    }
  }
}

__global__ void init_kernel(const float* __restrict__ h0,
                            _Float16* __restrict__ h0b1, _Float16* __restrict__ h1b1,
                            _Float16* __restrict__ yb1){
  int i = blockIdx.x*256 + threadIdx.x;
  if (i < BDIM*HDIM){
    h0b1[i] = (_Float16)h0[i];
    h1b1[i] = (_Float16)h0[BDIM*HDIM + i];
  }
  if (i < BDIM*ODIM) yb1[i] = (_Float16)(-2.0f); // SOS
}

__launch_bounds__(NTHR, 1)
__global__ void decoder_kernel(
    const float* __restrict__ Wih0, const float* __restrict__ Whh0,
    const float* __restrict__ bih0, const float* __restrict__ bhh0,
    const float* __restrict__ Wih1, const float* __restrict__ Whh1,
    const float* __restrict__ bih1, const float* __restrict__ bhh1,
    const float* __restrict__ Wfc,  const float* __restrict__ bfc,
    const float* __restrict__ c0in, float* __restrict__ out,
    char* __restrict__ ws)
{
  extern __shared__ char smem[];
  const int bid = blockIdx.x;
  const int tid = threadIdx.x;
  const int wv  = tid >> 6;
  const int ln  = tid & 63;
  const int l15 = ln & 15;
  const int lq  = ln >> 4;
  const int u0  = bid * 4;

  _Float16* yb[2]  = { (_Float16*)(ws + YB_OFF),  (_Float16*)(ws + YB_OFF  + YB_SZ) };
  _Float16* h0b[2] = { (_Float16*)(ws + H0B_OFF), (_Float16*)(ws + H0B_OFF + HB_SZ) };
  _Float16* h1b[2] = { (_Float16*)(ws + H1B_OFF), (_Float16*)(ws + H1B_OFF + HB_SZ) };
  unsigned int* fy  = (unsigned int*)(ws + FY_OFF);
  unsigned int* fh0 = (unsigned int*)(ws + FH0_OFF);
  unsigned int* fh1 = (unsigned int*)(ws + FH1_OFF);

  // ---- one-time: weights fp32->fp16 into LDS, exact fragment order ----
  for (int slot = tid; slot < WL0_NS*64; slot += NTHR){
    int s = slot >> 6, l = slot & 63;
    int r16 = l & 15, q = l >> 4;
    int grow = (r16 & 3)*HDIM + u0 + (r16 >> 2);
    int kb = s*32 + q*8;
    const float* src; int k0;
    if (kb < ODIM){ src = Wih0 + (size_t)grow*ODIM; k0 = kb; }
    else          { src = Whh0 + (size_t)grow*HDIM; k0 = kb - ODIM; }
    v8h hv;
    #pragma unroll
    for (int j = 0; j < 8; j++) hv[j] = (_Float16)src[k0 + j];
    *(v8h*)(smem + WL0_OFF + s*1024 + l*16) = hv;
  }
  for (int slot = tid; slot < WL1_NS*64; slot += NTHR){
    int s = slot >> 6, l = slot & 63;
    int r16 = l & 15, q = l >> 4;
    int grow = (r16 & 3)*HDIM + u0 + (r16 >> 2);
    int kb = s*32 + q*8;
    const float* src; int k0;
    if (kb < HDIM){ src = Wih1 + (size_t)grow*HDIM; k0 = kb; }
    else          { src = Whh1 + (size_t)grow*HDIM; k0 = kb - HDIM; }
    v8h hv;
    #pragma unroll
    for (int j = 0; j < 8; j++) hv[j] = (_Float16)src[k0 + j];
    *(v8h*)(smem + WL1_OFF + s*1024 + l*16) = hv;
  }
  if (bid < 32){
    for (int slot = tid; slot < WFC_NS*64; slot += NTHR){
      int s = slot >> 6, l = slot & 63;
      int r16 = l & 15, q = l >> 4;
      const float* src = Wfc + (size_t)(bid*16 + r16)*HDIM;
      int k0 = s*32 + q*8;
      v8h hv;
      #pragma unroll
      for (int j = 0; j < 8; j++) hv[j] = (_Float16)src[k0 + j];
      *(v8h*)(smem + WFC_OFF + s*1024 + l*16) = hv;
    }
  }
  __syncthreads();

  // ---- per-lane constants ----
  const int gidx = l15 & 3;
  const int unit = u0 + (l15 >> 2);
  const int growL = gidx*HDIM + unit;
  const float bias0 = bih0[growL] + bhh0[growL];
  const float bias1 = bih1[growL] + bhh1[growL];
  float biasf = 0.f;
  if (bid < 32) biasf = bfc[bid*16 + l15];

  const int rb = wv*16 + lq*4;
  float cs0[4], cs1[4];
  #pragma unroll
  for (int r = 0; r < 4; r++){
    int b = rb + r;
    cs0[r] = c0in[(size_t)(0*BDIM + b)*HDIM + unit];
    cs1[r] = c0in[(size_t)(1*BDIM + b)*HDIM + unit];
  }

  const int row = wv*16 + l15;
  const size_t aoffY = (size_t)row*ODIM*2 + (size_t)lq*16;
  const size_t aoffH = (size_t)row*HDIM*2 + (size_t)lq*16;
  const size_t hwoff = ((size_t)rb*HDIM + u0)*2;   // h-store base (l15==0 lanes)
  const char* wl0 = smem + WL0_OFF + ln*16;
  const char* wl1 = smem + WL1_OFF + ln*16;
  const char* wlf = smem + WFC_OFF + ln*16;
  const char* wl0r = wl0 + 16*1024;   // Whh0 slices
  const char* wl1r = wl1 + 32*1024;   // Whh1 slices

  // prologue: p0 = Whh0 @ h0_init (init buffers visible: kernel-boundary release)
  v4f p0 = {0.f,0.f,0.f,0.f};
  {
    const char* hi = (const char*)h0b[1] + aoffH;
    const char* cb[4] = { hi, hi+512, hi+1024, hi+1536 };
    p0 = gemm_phase<4>(cb, wl0r, p0);
  }

  for (int t = 0; t < SEQL; t++){
    const int pi = (t + 1) & 1;
    const int pc = t & 1;

    // -- stage 1: wait y[t-1]
    if (t > 0) wait_flags(fy, 32, (unsigned)t);

    // -- stage 2: L0 input part (K=512) + recurrent partial
    {
      const char* ysrc = (const char*)yb[pi] + aoffY;
      const char* cb[2] = { ysrc, ysrc+512 };
      v4f acc = gemm_phase<2>(cb, wl0, p0);
      lstm_epi_pack(acc, bias0, cs0, (char*)h0b[pc] + hwoff, l15, gidx);
    }
    publish_flag(fh0 + bid*FSTRIDE, (unsigned)(t+1));

    // -- stage 3 (off critical path): p1 = Whh1 @ h1[t-1]
    v4f p1 = {0.f,0.f,0.f,0.f};
    {
      const char* hs = (const char*)h1b[pi] + aoffH;
      const char* cb[4] = { hs, hs+512, hs+1024, hs+1536 };
      p1 = gemm_phase<4>(cb, wl1r, p1);
    }

    // -- stage 4: wait h0[t]
    wait_flags(fh0, 256, (unsigned)(t+1));

    // -- stage 5: L1 input part + fused next-step L0 recurrent (shared A)
    {
      const char* hs = (const char*)h0b[pc] + aoffH;
      const char* cb[4] = { hs, hs+512, hs+1024, hs+1536 };
      v4f np0 = {0.f,0.f,0.f,0.f};
      gemm_dual4(cb, wl1, wl0r, p1, np0);
      lstm_epi_pack(p1, bias1, cs1, (char*)h1b[pc] + hwoff, l15, gidx);
      p0 = np0;
    }
    publish_flag(fh1 + bid*FSTRIDE, (unsigned)(t+1));

    // -- stage 6 (blocks 0..31): FC -> y[t]
    if (bid < 32){
      wait_flags(fh1, 256, (unsigned)(t+1));
      const char* f = (const char*)h1b[pc] + aoffH;
      const char* cb[4] = { f, f+512, f+1024, f+1536 };
      v4f acc = {0.f,0.f,0.f,0.f};
      acc = gemm_phase<4>(cb, wlf, acc);
      #pragma unroll
      for (int r = 0; r < 4; r++){
        float v = fmaxf(acc[r] + biasf, 0.f);
        int b = rb + r;
        int o = bid*16 + l15;
        out[((size_t)b*SEQL + t)*ODIM + o] = v;
        unsigned int uv = (unsigned int)__builtin_bit_cast(unsigned short, (_Float16)v);
        unsigned int o1 = (unsigned int)__shfl_xor((int)uv, 1);
        unsigned int pr = uv | (o1 << 16);
        unsigned int o2 = (unsigned int)__shfl_xor((int)pr, 2);
        if ((l15 & 3) == 0){
          unsigned long long full = (unsigned long long)pr | ((unsigned long long)o2 << 32);
          __hip_atomic_store((unsigned long long*)((char*)yb[pc] + ((size_t)b*ODIM + o)*2),
                             full, __ATOMIC_RELAXED, __HIP_MEMORY_SCOPE_AGENT);
        }
      }
      publish_flag(fy + bid*FSTRIDE, (unsigned)(t+1));
    }
  }
}

extern "C" void kernel_launch(void* const* d_in, const int* in_sizes, int n_in,
                              void* d_out, int out_size, void* d_ws, size_t ws_size,
                              hipStream_t stream){
  (void)in_sizes; (void)n_in; (void)out_size;
  if (ws_size < (size_t)WS_NEED) return;

  const float* h0   = (const float*)d_in[1];
  const float* c0   = (const float*)d_in[2];
  const float* Wih0 = (const float*)d_in[3];
  const float* Whh0 = (const float*)d_in[4];
  const float* bih0 = (const float*)d_in[5];
  const float* bhh0 = (const float*)d_in[6];
  const float* Wih1 = (const float*)d_in[7];
  const float* Whh1 = (const float*)d_in[8];
  const float* bih1 = (const float*)d_in[9];
  const float* bhh1 = (const float*)d_in[10];
  const float* Wfc  = (const float*)d_in[11];
  const float* bfc  = (const float*)d_in[12];
  float* out = (float*)d_out;
  char* ws = (char*)d_ws;

  (void)hipMemsetAsync(ws + FLG_OFF, 0, FLG_BYTES, stream);
  hipLaunchKernelGGL(init_kernel, dim3(256), dim3(256), 0, stream,
                     h0,
                     (_Float16*)(ws + H0B_OFF + HB_SZ),
                     (_Float16*)(ws + H1B_OFF + HB_SZ),
                     (_Float16*)(ws + YB_OFF + YB_SZ));

  (void)hipFuncSetAttribute((const void*)decoder_kernel,
                            hipFuncAttributeMaxDynamicSharedMemorySize, SMEM_BYTES);
  hipLaunchKernelGGL(decoder_kernel, dim3(NBLK), dim3(NTHR), SMEM_BYTES, stream,
                     Wih0, Whh0, bih0, bhh0, Wih1, Whh1, bih1, bhh1,
                     Wfc, bfc, c0, out, ws);
}